// Round 7
// baseline (1268.805 us; speedup 1.0000x reference)
//
#include <hip/hip_runtime.h>
#include <cstddef>

// ---------------------------------------------------------------------------
// GCN forward: 3 x ( h@W bf16 MFMA -> packed-bf16 xw -> CSR segsum+LN(+ReLU) )
// N=50000, E=800000, D: 128 -> 128 -> 128 -> 64.
// R20 = R19's single-kernel plan with a CAPTURE-SAFE software grid barrier
// (R19's hipLaunchCooperativeKernel was rejected under graph capture ->
// kernel never ran -> absmax = max|ref|):
//  - One persistent kernel, 1024 blocks x 256 thr, __launch_bounds__(256,4)
//    (VGPR<=128 -> 16 waves/CU -> 4 blocks/CU -> all 1024 blocks resident).
//  - gbar(): per-thread threadfence (agent release, L2 wb) + atomic arrive +
//    acquire spin + threadfence (invalidate). Counters zeroed per launch via
//    hipMemsetAsync (graph-capturable).
//  - Stage bodies byte-identical to R15's proven 189us versions.
// ---------------------------------------------------------------------------

typedef __attribute__((ext_vector_type(8))) short bf16x8;
typedef __attribute__((ext_vector_type(4))) float floatx4;
typedef __attribute__((ext_vector_type(4))) unsigned int uintx4;
typedef __attribute__((ext_vector_type(2))) unsigned int uintx2;

static __device__ __forceinline__ unsigned int f2bf(float f) {
    union { float f; unsigned int u; } v; v.f = f;
    unsigned int u = v.u;
    u += 0x7fffu + ((u >> 16) & 1u);
    return u >> 16;
}
static __device__ __forceinline__ float bf_lo(unsigned int p) {
    union { unsigned int u; float f; } v; v.u = p << 16; return v.f;
}
static __device__ __forceinline__ float bf_hi(unsigned int p) {
    union { unsigned int u; float f; } v; v.u = p & 0xffff0000u; return v.f;
}
static __device__ __forceinline__ void acc8(float* a, uintx4 v) {
    a[0] += bf_lo(v.x); a[1] += bf_hi(v.x);
    a[2] += bf_lo(v.y); a[3] += bf_hi(v.y);
    a[4] += bf_lo(v.z); a[5] += bf_hi(v.z);
    a[6] += bf_lo(v.w); a[7] += bf_hi(v.w);
}
static __device__ __forceinline__ void acc4(float* a, uintx2 v) {
    a[0] += bf_lo(v.x); a[1] += bf_hi(v.x);
    a[2] += bf_lo(v.y); a[3] += bf_hi(v.y);
}

// ---- device-scope grid barrier (capture-safe persistent-kernel sync) -------
static __device__ __forceinline__ void gbar(unsigned int* ctr, int nb) {
    __threadfence();                 // release: this thread's writes -> device scope
    __syncthreads();                 // whole block done + fenced
    if (threadIdx.x == 0) {
        __hip_atomic_fetch_add(ctr, 1u, __ATOMIC_ACQ_REL, __HIP_MEMORY_SCOPE_AGENT);
        while (__hip_atomic_load(ctr, __ATOMIC_ACQUIRE, __HIP_MEMORY_SCOPE_AGENT)
               < (unsigned int)nb)
            __builtin_amdgcn_s_sleep(2);
    }
    __syncthreads();
    __threadfence();                 // acquire: invalidate stale cached lines
}

// ---- stage 0: W[k][n] fp32 -> FRAGMENT-ORDERED WtF (48 logical slices) -----
static __device__ __forceinline__ void cvtw_slice(int b,
        const float* __restrict__ W0, const float* __restrict__ W1,
        const float* __restrict__ W2, unsigned int* __restrict__ WtF) {
    const int m = b >> 4;
    const int slice = b & 15;
    const float* W = (m == 0) ? W0 : (m == 1) ? W1 : W2;
    const int ncols = (m == 2) ? 64 : 128;
    unsigned int* dst = WtF + m * 128 * 64;
    const int total = ncols * 64;                  // uints
    for (int idx = slice * 256 + threadIdx.x; idx < total; idx += 16 * 256) {
        const int j    = idx & 3;
        const int lane = (idx >> 2) & 63;
        const int s    = (idx >> 8) & 3;
        const int t    = idx >> 10;
        const int mcol = lane & 15;
        const int quad = lane >> 4;
        const int n = t * 16 + mcol;
        const int k = s * 32 + quad * 8 + 2 * j;
        unsigned int lo = f2bf(W[(size_t)k * ncols + n]);
        unsigned int hi = f2bf(W[(size_t)(k + 1) * ncols + n]);
        dst[idx] = (hi << 16) | lo;
    }
}

// ---- stage 1: bf16 MFMA GEMM, one 16-row tile per wave, fp32 A path --------
static __device__ __forceinline__ void gemm0_tile(int tile,
        const float* __restrict__ feat, const unsigned int* __restrict__ Wt,
        unsigned int* __restrict__ C, int M, int lane) {
    const int row0 = tile * 16;
    const int quad = lane >> 4;
    const int mcol = lane & 15;

    constexpr int NT = 8;                        // 128 cols
    floatx4 acc[NT];
    #pragma unroll
    for (int t = 0; t < NT; ++t) acc[t] = (floatx4){0.f, 0.f, 0.f, 0.f};

    int aidx = row0 + mcol; if (aidx >= M) aidx = M - 1;
    const float*        arowF = feat + (size_t)aidx * 128 + quad * 8;
    const unsigned int* bbase = Wt + lane * 4;

    #pragma unroll
    for (int s = 0; s < 4; ++s) {
        float4 fa = *(const float4*)(arowF + s * 32);
        float4 fb = *(const float4*)(arowF + s * 32 + 4);
        uintx4 ap;
        ap.x = (f2bf(fa.y) << 16) | f2bf(fa.x);
        ap.y = (f2bf(fa.w) << 16) | f2bf(fa.z);
        ap.z = (f2bf(fb.y) << 16) | f2bf(fb.x);
        ap.w = (f2bf(fb.w) << 16) | f2bf(fb.z);
        bf16x8 a = __builtin_bit_cast(bf16x8, ap);
        #pragma unroll
        for (int t = 0; t < NT; ++t) {
            uintx4 bp = *(const uintx4*)(bbase + t * 1024 + s * 256);
            bf16x8 b = __builtin_bit_cast(bf16x8, bp);
            acc[t] = __builtin_amdgcn_mfma_f32_16x16x32_bf16(a, b, acc[t], 0, 0, 0);
        }
    }

    #pragma unroll
    for (int t = 0; t < NT; ++t) {
        #pragma unroll
        for (int r = 0; r < 4; ++r) {
            unsigned int mybf = f2bf(acc[t][r]);
            unsigned int pair = __shfl_xor(mybf, 1, 64);
            int orow = row0 + quad * 4 + r;
            if (orow < M && (mcol & 1) == 0) {
                unsigned int packed = (pair << 16) | mybf;
                C[(size_t)orow * 64 + t * 8 + (mcol >> 1)] = packed;
            }
        }
    }
}

// ---- stages 2,3: CSR segsum + LN + ReLU -> LDS A-tile -> MFMA x W ----------
// Block = 16-node tile, 4 waves x 4 nodes, R15 2-deep pipelined gather.
template <int NCOLS_OUT>
static __device__ __forceinline__ void agg_gemm_tile(int tile,
        const unsigned int* __restrict__ xw, const int* __restrict__ ptr,
        const int* __restrict__ col, const unsigned int* __restrict__ Wt,
        unsigned int* __restrict__ C, int N, int Emax,
        unsigned int* lds /* 1024 uints */) {
    const int wave = threadIdx.x >> 6;
    const int lane = threadIdx.x & 63;
    const int g  = lane >> 4;     // 0..3 edge group
    const int sl = lane & 15;     // 0..15 sublane (owns 8 features)

    int s0[4], len[4];
    int maxlen = 0;
    #pragma unroll
    for (int n = 0; n < 4; ++n) {
        const int node = tile * 16 + wave * 4 + n;
        const int nc = node < N ? node : N - 1;
        const int a = ptr[nc];
        const int b = node < N ? ptr[nc + 1] : a;
        s0[n] = a; len[n] = b - a;
        maxlen = max(maxlen, len[n]);
    }

    float acc[4][8] = {};
    const unsigned int* base = xw + sl * 4;

    if (maxlen > 0) {
        #define LOADCOL(dst, OFF)                                            \
            _Pragma("unroll")                                                \
            for (int n = 0; n < 4; ++n) {                                    \
                int idx = (OFF) + g;                                         \
                idx = idx < len[n] ? idx : 0;                                \
                int ei = s0[n] + idx;                                        \
                ei = ei < Emax ? ei : Emax;                                  \
                dst[n] = col[ei];                                            \
            }
        #define GATHER4(dst, c)                                              \
            _Pragma("unroll")                                                \
            for (int n = 0; n < 4; ++n)                                      \
                dst[n] = *(const uintx4*)(base + (size_t)c[n] * 64);
        #define ACCUM4(v, OFF)                                               \
            _Pragma("unroll")                                                \
            for (int n = 0; n < 4; ++n)                                      \
                if ((OFF) + g < len[n]) acc8(acc[n], v[n]);

        int cA[4], cB[4], cC[4], cD[4];
        uintx4 vA[4], vB[4];
        LOADCOL(cA, 0)
        LOADCOL(cB, 4)
        GATHER4(vA, cA)
        LOADCOL(cC, 8)
        GATHER4(vB, cB)
        LOADCOL(cD, 12)

        const int rounds = (maxlen + 7) & ~7;
        for (int off = 0; off < rounds; off += 8) {
            ACCUM4(vA, off)
            GATHER4(vA, cC)            // data for off+8
            LOADCOL(cC, off + 16)
            ACCUM4(vB, off + 4)
            GATHER4(vB, cD)            // data for off+12
            LOADCOL(cD, off + 20)
        }
        #undef LOADCOL
        #undef GATHER4
        #undef ACCUM4
    }

    // ---- LN + ReLU per node, write LDS A-frag tile ----
    #pragma unroll
    for (int n = 0; n < 4; ++n) {
        const int m = wave * 4 + n;
        float a8[8];
        #pragma unroll
        for (int j = 0; j < 8; ++j) {
            float t = acc[n][j];
            t += __shfl_xor(t, 16, 64);
            t += __shfl_xor(t, 32, 64);
            a8[j] = t;
        }
        float s1 = 0.f, s2 = 0.f;
        #pragma unroll
        for (int j = 0; j < 8; ++j) { s1 += a8[j]; s2 += a8[j] * a8[j]; }
        #pragma unroll
        for (int mm = 8; mm >= 1; mm >>= 1) {
            s1 += __shfl_xor(s1, mm, 64);
            s2 += __shfl_xor(s2, mm, 64);
        }
        const float mean = s1 * (1.0f / 128.0f);
        const float var  = s2 * (1.0f / 128.0f) - mean * mean;
        const float inv  = rsqrtf(var + 1e-5f);

        if (g == 0) {
            float o[8];
            #pragma unroll
            for (int j = 0; j < 8; ++j)
                o[j] = fmaxf((a8[j] - mean) * inv, 0.f);
            uintx4 p;
            p.x = (f2bf(o[1]) << 16) | f2bf(o[0]);
            p.y = (f2bf(o[3]) << 16) | f2bf(o[2]);
            p.z = (f2bf(o[5]) << 16) | f2bf(o[4]);
            p.w = (f2bf(o[7]) << 16) | f2bf(o[6]);
            *(uintx4*)(lds + (sl >> 2) * 256 + (sl & 3) * 64 + m * 4) = p;
        }
    }
    __syncthreads();

    // ---- phase 2: 16 x NCOLS_OUT MFMA, wave covers NCOLS_OUT/4 cols --------
    constexpr int WT = NCOLS_OUT / 64;           // tiles per wave (2 or 1)
    const int quad = lane >> 4;
    const int mcol = lane & 15;
    floatx4 macc[WT];
    #pragma unroll
    for (int t = 0; t < WT; ++t) macc[t] = (floatx4){0.f, 0.f, 0.f, 0.f};

    const unsigned int* bbase = Wt + lane * 4;
    #pragma unroll
    for (int s4 = 0; s4 < 4; ++s4) {
        uintx4 ap = *(const uintx4*)(lds + s4 * 256 + lane * 4);
        bf16x8 a = __builtin_bit_cast(bf16x8, ap);
        #pragma unroll
        for (int tt = 0; tt < WT; ++tt) {
            const int t = wave * WT + tt;
            uintx4 bp = *(const uintx4*)(bbase + t * 1024 + s4 * 256);
            bf16x8 b = __builtin_bit_cast(bf16x8, bp);
            macc[tt] = __builtin_amdgcn_mfma_f32_16x16x32_bf16(a, b, macc[tt], 0, 0, 0);
        }
    }

    const int rowStride = NCOLS_OUT >> 1;
    #pragma unroll
    for (int tt = 0; tt < WT; ++tt) {
        const int t = wave * WT + tt;
        #pragma unroll
        for (int r = 0; r < 4; ++r) {
            unsigned int mybf = f2bf(macc[tt][r]);
            unsigned int pair = __shfl_xor(mybf, 1, 64);
            const int orow = tile * 16 + quad * 4 + r;
            if (orow < N && (mcol & 1) == 0) {
                unsigned int packed = (pair << 16) | mybf;
                C[(size_t)orow * rowStride + t * 8 + (mcol >> 1)] = packed;
            }
        }
    }
}

// ---- stage 4: CSR segsum + LN, D=64, fp32 out, no ReLU ---------------------
static __device__ __forceinline__ void agg_ln64_tile(int tile,
        const unsigned int* __restrict__ xw, const int* __restrict__ ptr,
        const int* __restrict__ col, float* __restrict__ out,
        int N, int Emax) {
    const int wave = threadIdx.x >> 6;
    const int lane = threadIdx.x & 63;
    const int g  = lane >> 4;     // 0..3 edge group
    const int sl = lane & 15;     // 0..15 sublane (owns 4 features)

    int s0[4], len[4];
    int maxlen = 0;
    #pragma unroll
    for (int n = 0; n < 4; ++n) {
        const int node = tile * 16 + wave * 4 + n;
        const int nc = node < N ? node : N - 1;
        const int a = ptr[nc];
        const int b = node < N ? ptr[nc + 1] : a;
        s0[n] = a; len[n] = b - a;
        maxlen = max(maxlen, len[n]);
    }

    float acc[4][4] = {};
    const unsigned int* base = xw + sl * 2;

    if (maxlen > 0) {
        #define LOADCOL(dst, OFF)                                            \
            _Pragma("unroll")                                                \
            for (int n = 0; n < 4; ++n) {                                    \
                int idx = (OFF) + g;                                         \
                idx = idx < len[n] ? idx : 0;                                \
                int ei = s0[n] + idx;                                        \
                ei = ei < Emax ? ei : Emax;                                  \
                dst[n] = col[ei];                                            \
            }
        #define GATHER2(dst, c)                                              \
            _Pragma("unroll")                                                \
            for (int n = 0; n < 4; ++n)                                      \
                dst[n] = *(const uintx2*)(base + (size_t)c[n] * 32);
        #define ACCUM2(v, OFF)                                               \
            _Pragma("unroll")                                                \
            for (int n = 0; n < 4; ++n)                                      \
                if ((OFF) + g < len[n]) acc4(acc[n], v[n]);

        int cA[4], cB[4], cC[4], cD[4];
        uintx2 vA[4], vB[4];
        LOADCOL(cA, 0)
        LOADCOL(cB, 4)
        GATHER2(vA, cA)
        LOADCOL(cC, 8)
        GATHER2(vB, cB)
        LOADCOL(cD, 12)

        const int rounds = (maxlen + 7) & ~7;
        for (int off = 0; off < rounds; off += 8) {
            ACCUM2(vA, off)
            GATHER2(vA, cC)
            LOADCOL(cC, off + 16)
            ACCUM2(vB, off + 4)
            GATHER2(vB, cD)
            LOADCOL(cD, off + 20)
        }
        #undef LOADCOL
        #undef GATHER2
        #undef ACCUM2
    }

    #pragma unroll
    for (int n = 0; n < 4; ++n) {
        const int node = tile * 16 + wave * 4 + n;
        float a4[4];
        #pragma unroll
        for (int j = 0; j < 4; ++j) {
            float t = acc[n][j];
            t += __shfl_xor(t, 16, 64);
            t += __shfl_xor(t, 32, 64);
            a4[j] = t;
        }
        float s1 = 0.f, s2 = 0.f;
        #pragma unroll
        for (int j = 0; j < 4; ++j) { s1 += a4[j]; s2 += a4[j] * a4[j]; }
        #pragma unroll
        for (int mm = 8; mm >= 1; mm >>= 1) {
            s1 += __shfl_xor(s1, mm, 64);
            s2 += __shfl_xor(s2, mm, 64);
        }
        const float mean = s1 * (1.0f / 64.0f);
        const float var  = s2 * (1.0f / 64.0f) - mean * mean;
        const float inv  = rsqrtf(var + 1e-5f);

        if (g == 0 && node < N) {
            float4 o;
            o.x = (a4[0] - mean) * inv;
            o.y = (a4[1] - mean) * inv;
            o.z = (a4[2] - mean) * inv;
            o.w = (a4[3] - mean) * inv;
            *(float4*)(out + (size_t)node * 64 + sl * 4) = o;
        }
    }
}

// ---- the whole net in one persistent dispatch ------------------------------
__global__ __launch_bounds__(256, 4) void gcn_all(
        const float* __restrict__ feat, const float* __restrict__ W0,
        const float* __restrict__ W1, const float* __restrict__ W2,
        const int* __restrict__ ptr, const int* __restrict__ col,
        unsigned int* __restrict__ buf0, unsigned int* __restrict__ buf1,
        unsigned int* __restrict__ WtP, unsigned int* __restrict__ ctrs,
        float* __restrict__ out, int N, int Emax, int tiles) {
    const int nb = gridDim.x;
    __shared__ unsigned int atile[1024];         // 4 KB A-frag tile

    // S0: weight conversion (48 logical slices)
    for (int b = blockIdx.x; b < 48; b += nb)
        cvtw_slice(b, W0, W1, W2, WtP);
    gbar(ctrs + 0, nb);

    // S1: layer-0 GEMM (fp32 feat A-path), one tile per wave
    {
        const int wave = threadIdx.x >> 6;
        const int lane = threadIdx.x & 63;
        const int q4 = (tiles + 3) / 4;
        for (int q = blockIdx.x; q < q4; q += nb) {
            const int tile = q * 4 + wave;
            if (tile < tiles) gemm0_tile(tile, feat, WtP, buf0, N, lane);
        }
    }
    gbar(ctrs + 16, nb);

    // S2: layer-0 agg+LN+ReLU fused with layer-1 GEMM
    for (int t = blockIdx.x; t < tiles; t += nb) {
        agg_gemm_tile<128>(t, buf0, ptr, col, WtP + 128 * 64, buf1, N, Emax, atile);
        __syncthreads();                         // atile reuse across iterations
    }
    gbar(ctrs + 32, nb);

    // S3: layer-1 agg+LN+ReLU fused with layer-2 GEMM (D_out=64)
    for (int t = blockIdx.x; t < tiles; t += nb) {
        agg_gemm_tile<64>(t, buf1, ptr, col, WtP + 2 * 128 * 64, buf0, N, Emax, atile);
        __syncthreads();
    }
    gbar(ctrs + 48, nb);

    // S4: layer-2 agg+LN (no ReLU), fp32 out
    for (int t = blockIdx.x; t < tiles; t += nb)
        agg_ln64_tile(t, buf0, ptr, col, out, N, Emax);
}

extern "C" void kernel_launch(void* const* d_in, const int* in_sizes, int n_in,
                              void* d_out, int out_size, void* d_ws, size_t ws_size,
                              hipStream_t stream) {
    const float* feat = (const float*)d_in[0];   // [N,128]
    const float* W0   = (const float*)d_in[1];   // [128,128]
    const float* W1   = (const float*)d_in[2];   // [128,128]
    const float* W2   = (const float*)d_in[3];   // [128,64]
    const int*   ptr  = (const int*)d_in[4];     // [N+1]
    const int*   col  = (const int*)d_in[5];     // [E]
    // d_in[6] = edge_rows, unused (CSR ptr encodes the same segments)

    const int N = in_sizes[4] - 1;               // 50000 (= 3125 * 16)
    const int E = in_sizes[5];                   // 800000
    const int Emax = E - 1;

    unsigned int* buf0 = (unsigned int*)d_ws;                // [N,64] uint, row-major packed
    unsigned int* buf1 = buf0 + (size_t)N * 64;              // [N,64] uint, row-major packed
    unsigned int* WtP  = buf1 + (size_t)N * 64;              // 3 x frag-ordered W
    unsigned int* ctrs = WtP + 3 * 128 * 64;                 // 4 barrier counters (64B apart)
    float*        out  = (float*)d_out;                      // [N,64]

    const int tiles = (N + 15) / 16;             // 3125 (16-node tiles)

    hipMemsetAsync(ctrs, 0, 256, stream);        // zero barrier counters (capture-safe)

    gcn_all<<<1024, 256, 0, stream>>>(feat, W0, W1, W2, ptr, col,
                                      buf0, buf1, WtP, ctrs, out,
                                      N, Emax, tiles);
}

// Round 12
// 193.971 us; speedup vs baseline: 6.5412x; 6.5412x over previous
//
#include <hip/hip_runtime.h>
#include <cstddef>

// ---------------------------------------------------------------------------
// GCN forward: 3 x ( h@W bf16 MFMA -> packed-bf16 xw -> CSR segsum+LN(+ReLU) )
// N=50000, E=800000, D: 128 -> 128 -> 128 -> 64.
// R21 = R15 bodies (best verified: 189us; R20's persistent kernel = 1268us,
// per-thread device fences are catastrophic) + DISPATCH-BOUNDARY REDUCTION:
//  - R20 datum: single-dispatch wall == kernel dur exactly -> R15's 189us
//    wall vs ~123us kernel-sum means ~66us sits in 4 dependent-dispatch
//    boundaries (L2 wb+inv across 8 XCDs, ~13-16us each).
//  - cvt_w dispatch eliminated: gemm0 blocks convert W0 into their own LDS
//    (B served from LDS, 32KB -> same 4 blocks/CU) and blocks 0..31 also
//    emit fragment-ordered W1/W2 to global WtP for the agg dispatches.
//  - Chain: [gemm0_all][agg128][agg64][agg_ln64] = 3 boundaries (was 4+cvt).
//  - agg kernels byte-identical to R15.
// (R25 resubmission: R21..R24 never ran -- GPU acquisition timeouts.)
// ---------------------------------------------------------------------------

typedef __attribute__((ext_vector_type(8))) short bf16x8;
typedef __attribute__((ext_vector_type(4))) float floatx4;
typedef __attribute__((ext_vector_type(4))) unsigned int uintx4;
typedef __attribute__((ext_vector_type(2))) unsigned int uintx2;

static __device__ __forceinline__ unsigned int f2bf(float f) {
    union { float f; unsigned int u; } v; v.f = f;
    unsigned int u = v.u;
    u += 0x7fffu + ((u >> 16) & 1u);
    return u >> 16;
}
static __device__ __forceinline__ float bf_lo(unsigned int p) {
    union { unsigned int u; float f; } v; v.u = p << 16; return v.f;
}
static __device__ __forceinline__ float bf_hi(unsigned int p) {
    union { unsigned int u; float f; } v; v.u = p & 0xffff0000u; return v.f;
}
static __device__ __forceinline__ void acc8(float* a, uintx4 v) {
    a[0] += bf_lo(v.x); a[1] += bf_hi(v.x);
    a[2] += bf_lo(v.y); a[3] += bf_hi(v.y);
    a[4] += bf_lo(v.z); a[5] += bf_hi(v.z);
    a[6] += bf_lo(v.w); a[7] += bf_hi(v.w);
}
static __device__ __forceinline__ void acc4(float* a, uintx2 v) {
    a[0] += bf_lo(v.x); a[1] += bf_hi(v.x);
    a[2] += bf_lo(v.y); a[3] += bf_hi(v.y);
}

// Fragment-order conversion: uint idx = t*1024 + s*256 + lane*4 + j holds
// packed bf16 pair W[k][n],W[k+1][n], n = t*16+(lane&15), k = s*32+(lane>>4)*8+2j.
static __device__ __forceinline__ void cvt_block(const float* __restrict__ W,
                                                 int ncols,
                                                 unsigned int* __restrict__ dst,
                                                 int tid0, int stride, int total) {
    for (int idx = tid0; idx < total; idx += stride) {
        const int j    = idx & 3;
        const int lane = (idx >> 2) & 63;
        const int s    = (idx >> 8) & 3;
        const int t    = idx >> 10;
        const int mcol = lane & 15;
        const int quad = lane >> 4;
        const int n = t * 16 + mcol;
        const int k = s * 32 + quad * 8 + 2 * j;
        unsigned int lo = f2bf(W[(size_t)k * ncols + n]);
        unsigned int hi = f2bf(W[(size_t)(k + 1) * ncols + n]);
        dst[idx] = (hi << 16) | lo;
    }
}

// ---- dispatch 1: W0->LDS convert + layer-0 GEMM (+ W1/W2 -> global WtP) ----
// 4 waves/block, each wave one 16-row tile. B (W0 frag-ordered) in LDS.
__global__ __launch_bounds__(256) void gemm0_all(const float* __restrict__ feat,
                                                 const float* __restrict__ W0,
                                                 const float* __restrict__ W1,
                                                 const float* __restrict__ W2,
                                                 unsigned int* __restrict__ WtP,
                                                 unsigned int* __restrict__ C,
                                                 int M, int tiles) {
    __shared__ unsigned int wb[8192];            // 32 KB: W0 fragment-ordered

    // (a) every block: W0 -> LDS
    cvt_block(W0, 128, wb, threadIdx.x, 256, 8192);

    // (b) blocks 0..31: W1/W2 slices -> global WtP (for the agg dispatches)
    if (blockIdx.x < 32) {
        const int m = 1 + (blockIdx.x >> 4);     // 1 or 2
        const int slice = blockIdx.x & 15;
        const float* W = (m == 1) ? W1 : W2;
        const int ncols = (m == 2) ? 64 : 128;
        const int total = ncols * 64;
        cvt_block(W, ncols, WtP + m * 8192, slice * 256 + threadIdx.x, 16 * 256, total);
    }
    __syncthreads();

    const int wave = threadIdx.x >> 6;
    const int lane = threadIdx.x & 63;
    const int tile = blockIdx.x * 4 + wave;
    if (tile >= tiles) return;
    const int row0 = tile * 16;
    const int quad = lane >> 4;
    const int mcol = lane & 15;

    constexpr int NT = 8;                        // 128 cols
    floatx4 acc[NT];
    #pragma unroll
    for (int t = 0; t < NT; ++t) acc[t] = (floatx4){0.f, 0.f, 0.f, 0.f};

    int aidx = row0 + mcol; if (aidx >= M) aidx = M - 1;
    const float* arowF = feat + (size_t)aidx * 128 + quad * 8;
    const unsigned int* bbase = wb + lane * 4;

    #pragma unroll
    for (int s = 0; s < 4; ++s) {
        float4 fa = *(const float4*)(arowF + s * 32);
        float4 fb = *(const float4*)(arowF + s * 32 + 4);
        uintx4 ap;
        ap.x = (f2bf(fa.y) << 16) | f2bf(fa.x);
        ap.y = (f2bf(fa.w) << 16) | f2bf(fa.z);
        ap.z = (f2bf(fb.y) << 16) | f2bf(fb.x);
        ap.w = (f2bf(fb.w) << 16) | f2bf(fb.z);
        bf16x8 a = __builtin_bit_cast(bf16x8, ap);
        #pragma unroll
        for (int t = 0; t < NT; ++t) {
            uintx4 bp = *(const uintx4*)(bbase + t * 1024 + s * 256);
            bf16x8 b = __builtin_bit_cast(bf16x8, bp);
            acc[t] = __builtin_amdgcn_mfma_f32_16x16x32_bf16(a, b, acc[t], 0, 0, 0);
        }
    }

    #pragma unroll
    for (int t = 0; t < NT; ++t) {
        #pragma unroll
        for (int r = 0; r < 4; ++r) {
            unsigned int mybf = f2bf(acc[t][r]);
            unsigned int pair = __shfl_xor(mybf, 1, 64);
            int orow = row0 + quad * 4 + r;
            if (orow < M && (mcol & 1) == 0) {
                unsigned int packed = (pair << 16) | mybf;
                C[(size_t)orow * 64 + t * 8 + (mcol >> 1)] = packed;
            }
        }
    }
}

// ---- dispatches 2,3: CSR segsum + LN + ReLU -> LDS A-tile -> MFMA x W ------
// R15 body, unchanged. Block = 16-node tile, 4 waves x 4 nodes, 2-deep
// pipelined concurrent gather.
template <int NCOLS_OUT>
__global__ __launch_bounds__(256) void agg_gemm(const unsigned int* __restrict__ xw,
                                                const int* __restrict__ ptr,
                                                const int* __restrict__ col,
                                                const unsigned int* __restrict__ Wt,
                                                unsigned int* __restrict__ C,
                                                int N, int Emax /* = E-1 */) {
    __shared__ unsigned int lds[1024];           // 16 rows x 128 bf16, A-frag order
    const int tile = blockIdx.x;
    const int wave = threadIdx.x >> 6;
    const int lane = threadIdx.x & 63;
    const int g  = lane >> 4;     // 0..3 edge group
    const int sl = lane & 15;     // 0..15 sublane (owns 8 features)

    int s0[4], len[4];
    int maxlen = 0;
    #pragma unroll
    for (int n = 0; n < 4; ++n) {
        const int node = tile * 16 + wave * 4 + n;
        const int nc = node < N ? node : N - 1;
        const int a = ptr[nc];
        const int b = node < N ? ptr[nc + 1] : a;
        s0[n] = a; len[n] = b - a;
        maxlen = max(maxlen, len[n]);
    }

    float acc[4][8] = {};
    const unsigned int* base = xw + sl * 4;

    if (maxlen > 0) {
        #define LOADCOL(dst, OFF)                                            \
            _Pragma("unroll")                                                \
            for (int n = 0; n < 4; ++n) {                                    \
                int idx = (OFF) + g;                                         \
                idx = idx < len[n] ? idx : 0;                                \
                int ei = s0[n] + idx;                                        \
                ei = ei < Emax ? ei : Emax;                                  \
                dst[n] = col[ei];                                            \
            }
        #define GATHER4(dst, c)                                              \
            _Pragma("unroll")                                                \
            for (int n = 0; n < 4; ++n)                                      \
                dst[n] = *(const uintx4*)(base + (size_t)c[n] * 64);
        #define ACCUM4(v, OFF)                                               \
            _Pragma("unroll")                                                \
            for (int n = 0; n < 4; ++n)                                      \
                if ((OFF) + g < len[n]) acc8(acc[n], v[n]);

        int cA[4], cB[4], cC[4], cD[4];
        uintx4 vA[4], vB[4];
        LOADCOL(cA, 0)
        LOADCOL(cB, 4)
        GATHER4(vA, cA)
        LOADCOL(cC, 8)
        GATHER4(vB, cB)
        LOADCOL(cD, 12)

        const int rounds = (maxlen + 7) & ~7;
        for (int off = 0; off < rounds; off += 8) {
            ACCUM4(vA, off)
            GATHER4(vA, cC)            // data for off+8
            LOADCOL(cC, off + 16)
            ACCUM4(vB, off + 4)
            GATHER4(vB, cD)            // data for off+12
            LOADCOL(cD, off + 20)
        }
        #undef LOADCOL
        #undef GATHER4
        #undef ACCUM4
    }

    // ---- LN + ReLU per node, write LDS A-frag tile ----
    #pragma unroll
    for (int n = 0; n < 4; ++n) {
        const int m = wave * 4 + n;
        float a8[8];
        #pragma unroll
        for (int j = 0; j < 8; ++j) {
            float t = acc[n][j];
            t += __shfl_xor(t, 16, 64);
            t += __shfl_xor(t, 32, 64);
            a8[j] = t;
        }
        float s1 = 0.f, s2 = 0.f;
        #pragma unroll
        for (int j = 0; j < 8; ++j) { s1 += a8[j]; s2 += a8[j] * a8[j]; }
        #pragma unroll
        for (int mm = 8; mm >= 1; mm >>= 1) {
            s1 += __shfl_xor(s1, mm, 64);
            s2 += __shfl_xor(s2, mm, 64);
        }
        const float mean = s1 * (1.0f / 128.0f);
        const float var  = s2 * (1.0f / 128.0f) - mean * mean;
        const float inv  = rsqrtf(var + 1e-5f);

        if (g == 0) {
            float o[8];
            #pragma unroll
            for (int j = 0; j < 8; ++j)
                o[j] = fmaxf((a8[j] - mean) * inv, 0.f);
            uintx4 p;
            p.x = (f2bf(o[1]) << 16) | f2bf(o[0]);
            p.y = (f2bf(o[3]) << 16) | f2bf(o[2]);
            p.z = (f2bf(o[5]) << 16) | f2bf(o[4]);
            p.w = (f2bf(o[7]) << 16) | f2bf(o[6]);
            *(uintx4*)(lds + (sl >> 2) * 256 + (sl & 3) * 64 + m * 4) = p;
        }
    }
    __syncthreads();

    // ---- phase 2: 16 x NCOLS_OUT MFMA, wave covers NCOLS_OUT/4 cols --------
    constexpr int WT = NCOLS_OUT / 64;           // tiles per wave (2 or 1)
    const int quad = lane >> 4;
    const int mcol = lane & 15;
    floatx4 macc[WT];
    #pragma unroll
    for (int t = 0; t < WT; ++t) macc[t] = (floatx4){0.f, 0.f, 0.f, 0.f};

    const unsigned int* bbase = Wt + lane * 4;
    #pragma unroll
    for (int s4 = 0; s4 < 4; ++s4) {
        uintx4 ap = *(const uintx4*)(lds + s4 * 256 + lane * 4);
        bf16x8 a = __builtin_bit_cast(bf16x8, ap);
        #pragma unroll
        for (int tt = 0; tt < WT; ++tt) {
            const int t = wave * WT + tt;
            uintx4 bp = *(const uintx4*)(bbase + t * 1024 + s4 * 256);
            bf16x8 b = __builtin_bit_cast(bf16x8, bp);
            macc[tt] = __builtin_amdgcn_mfma_f32_16x16x32_bf16(a, b, macc[tt], 0, 0, 0);
        }
    }

    const int rowStride = NCOLS_OUT >> 1;
    #pragma unroll
    for (int tt = 0; tt < WT; ++tt) {
        const int t = wave * WT + tt;
        #pragma unroll
        for (int r = 0; r < 4; ++r) {
            unsigned int mybf = f2bf(macc[tt][r]);
            unsigned int pair = __shfl_xor(mybf, 1, 64);
            const int orow = tile * 16 + quad * 4 + r;
            if (orow < N && (mcol & 1) == 0) {
                unsigned int packed = (pair << 16) | mybf;
                C[(size_t)orow * rowStride + t * 8 + (mcol >> 1)] = packed;
            }
        }
    }
}

// ---- dispatch 4: CSR segsum + LN, D=64, fp32 out, no ReLU (R15 body) -------
__global__ __launch_bounds__(256) void agg_ln64(const unsigned int* __restrict__ xw,
                                                const int* __restrict__ ptr,
                                                const int* __restrict__ col,
                                                float* __restrict__ out,
                                                int N, int Emax) {
    const int tile = blockIdx.x;
    const int wave = threadIdx.x >> 6;
    const int lane = threadIdx.x & 63;
    const int g  = lane >> 4;     // 0..3 edge group
    const int sl = lane & 15;     // 0..15 sublane (owns 4 features)

    int s0[4], len[4];
    int maxlen = 0;
    #pragma unroll
    for (int n = 0; n < 4; ++n) {
        const int node = tile * 16 + wave * 4 + n;
        const int nc = node < N ? node : N - 1;
        const int a = ptr[nc];
        const int b = node < N ? ptr[nc + 1] : a;
        s0[n] = a; len[n] = b - a;
        maxlen = max(maxlen, len[n]);
    }

    float acc[4][4] = {};
    const unsigned int* base = xw + sl * 2;

    if (maxlen > 0) {
        #define LOADCOL(dst, OFF)                                            \
            _Pragma("unroll")                                                \
            for (int n = 0; n < 4; ++n) {                                    \
                int idx = (OFF) + g;                                         \
                idx = idx < len[n] ? idx : 0;                                \
                int ei = s0[n] + idx;                                        \
                ei = ei < Emax ? ei : Emax;                                  \
                dst[n] = col[ei];                                            \
            }
        #define GATHER2(dst, c)                                              \
            _Pragma("unroll")                                                \
            for (int n = 0; n < 4; ++n)                                      \
                dst[n] = *(const uintx2*)(base + (size_t)c[n] * 32);
        #define ACCUM2(v, OFF)                                               \
            _Pragma("unroll")                                                \
            for (int n = 0; n < 4; ++n)                                      \
                if ((OFF) + g < len[n]) acc4(acc[n], v[n]);

        int cA[4], cB[4], cC[4], cD[4];
        uintx2 vA[4], vB[4];
        LOADCOL(cA, 0)
        LOADCOL(cB, 4)
        GATHER2(vA, cA)
        LOADCOL(cC, 8)
        GATHER2(vB, cB)
        LOADCOL(cD, 12)

        const int rounds = (maxlen + 7) & ~7;
        for (int off = 0; off < rounds; off += 8) {
            ACCUM2(vA, off)
            GATHER2(vA, cC)
            LOADCOL(cC, off + 16)
            ACCUM2(vB, off + 4)
            GATHER2(vB, cD)
            LOADCOL(cD, off + 20)
        }
        #undef LOADCOL
        #undef GATHER2
        #undef ACCUM2
    }

    #pragma unroll
    for (int n = 0; n < 4; ++n) {
        const int node = tile * 16 + wave * 4 + n;
        float a4[4];
        #pragma unroll
        for (int j = 0; j < 4; ++j) {
            float t = acc[n][j];
            t += __shfl_xor(t, 16, 64);
            t += __shfl_xor(t, 32, 64);
            a4[j] = t;
        }
        float s1 = 0.f, s2 = 0.f;
        #pragma unroll
        for (int j = 0; j < 4; ++j) { s1 += a4[j]; s2 += a4[j] * a4[j]; }
        #pragma unroll
        for (int mm = 8; mm >= 1; mm >>= 1) {
            s1 += __shfl_xor(s1, mm, 64);
            s2 += __shfl_xor(s2, mm, 64);
        }
        const float mean = s1 * (1.0f / 64.0f);
        const float var  = s2 * (1.0f / 64.0f) - mean * mean;
        const float inv  = rsqrtf(var + 1e-5f);

        if (g == 0 && node < N) {
            float4 o;
            o.x = (a4[0] - mean) * inv;
            o.y = (a4[1] - mean) * inv;
            o.z = (a4[2] - mean) * inv;
            o.w = (a4[3] - mean) * inv;
            *(float4*)(out + (size_t)node * 64 + sl * 4) = o;
        }
    }
}

extern "C" void kernel_launch(void* const* d_in, const int* in_sizes, int n_in,
                              void* d_out, int out_size, void* d_ws, size_t ws_size,
                              hipStream_t stream) {
    const float* feat = (const float*)d_in[0];   // [N,128]
    const float* W0   = (const float*)d_in[1];   // [128,128]
    const float* W1   = (const float*)d_in[2];   // [128,128]
    const float* W2   = (const float*)d_in[3];   // [128,64]
    const int*   ptr  = (const int*)d_in[4];     // [N+1]
    const int*   col  = (const int*)d_in[5];     // [E]
    // d_in[6] = edge_rows, unused (CSR ptr encodes the same segments)

    const int N = in_sizes[4] - 1;               // 50000 (= 3125 * 16)
    const int E = in_sizes[5];                   // 800000
    const int Emax = E - 1;

    unsigned int* buf0 = (unsigned int*)d_ws;                // [N,64] uint, row-major packed
    unsigned int* buf1 = buf0 + (size_t)N * 64;              // [N,64] uint, row-major packed
    unsigned int* WtP  = buf1 + (size_t)N * 64;              // frag-ordered W (slots 0..2)
    float*        out  = (float*)d_out;                      // [N,64]

    const int tiles = (N + 15) / 16;             // 3125 (16-node tiles)

    // Dispatch 1: W0->LDS + layer-0 GEMM; also emits W1/W2 frag-ordered to WtP
    gemm0_all<<<(tiles + 3) / 4, 256, 0, stream>>>(feat, W0, W1, W2, WtP, buf0, N, tiles);
    // Dispatch 2: layer-0 agg+LN+ReLU fused with layer-1 GEMM
    agg_gemm<128><<<tiles, 256, 0, stream>>>(buf0, ptr, col, WtP + 8192, buf1, N, Emax);
    // Dispatch 3: layer-1 agg+LN+ReLU fused with layer-2 GEMM (D_out=64)
    agg_gemm<64><<<tiles, 256, 0, stream>>>(buf1, ptr, col, WtP + 2 * 8192, buf0, N, Emax);
    // Dispatch 4: layer-2 agg+LN (no ReLU), fp32 out
    agg_ln64<<<tiles, 256, 0, stream>>>(buf0, ptr, col, out, N, Emax);
}